// Round 11
// baseline (6513.461 us; speedup 1.0000x reference)
//
#include <hip/hip_runtime.h>
#include <hip/hip_cooperative_groups.h>
#include <math.h>

// AVWDCRNN round 11 (all-f32). r10=1343us, steady time dominated by ~96
// launch gaps. One cooperative persistent kernel per layer runs all 12 steps
// with grid.sync() between the 4 phases/step (phase bodies = r10's passed
// k_y/k_mm verbatim as device functions). Fallback to per-phase kernels if
// cooperative launch fails. k_y1x retiled (77us -> ~8us); biases merged.

#define NF __restrict__
namespace cg = cooperative_groups;
constexpr int N_ = 256, B_ = 8, T_ = 12, H_ = 64, E_ = 16;

__global__ void k_sentinel(float* NF out) { out[0] = 1.0e6f; }

// ---------------- adj = softmax(relu(ne ne^T), axis=1) ----------------
__global__ void k_adj(const float* NF ne, float* NF adj) {
    int n = blockIdx.x, m = threadIdx.x;
    __shared__ float en[E_];
    __shared__ float red[256];
    if (m < E_) en[m] = ne[n * E_ + m];
    __syncthreads();
    float s = 0.f;
#pragma unroll
    for (int d = 0; d < E_; d++) s += en[d] * ne[m * E_ + d];
    s = fmaxf(s, 0.f);
    red[m] = s; __syncthreads();
    for (int st = 128; st > 0; st >>= 1) { if (m < st) red[m] = fmaxf(red[m], red[m + st]); __syncthreads(); }
    float mx = red[0]; __syncthreads();
    float e = __expf(s - mx);
    red[m] = e; __syncthreads();
    for (int st = 128; st > 0; st >>= 1) { if (m < st) red[m] += red[m + st]; __syncthreads(); }
    adj[(size_t)n * N_ + m] = e / red[0];
}

// ------------- all four biases in one launch (grid 256, 192 thr) -------------
__global__ void k_bias4(const float* NF ne, const float* NF gb0, const float* NF ub0,
                        const float* NF gb1, const float* NF ub1,
                        float* NF Bg0, float* NF Bu0, float* NF Bg1, float* NF Bu1) {
    int n = blockIdx.x, tid = threadIdx.x;
    __shared__ float e[E_];
    if (tid < E_) e[tid] = ne[n * E_ + tid];
    __syncthreads();
    if (tid < 128) {
        float a0 = 0.f, a1 = 0.f;
#pragma unroll
        for (int d = 0; d < E_; d++) { a0 = fmaf(e[d], gb0[d * 128 + tid], a0); a1 = fmaf(e[d], gb1[d * 128 + tid], a1); }
        Bg0[(size_t)n * 128 + tid] = a0; Bg1[(size_t)n * 128 + tid] = a1;
    } else {
        int o = tid - 128;
        float a0 = 0.f, a1 = 0.f;
#pragma unroll
        for (int d = 0; d < E_; d++) { a0 = fmaf(e[d], ub0[d * 64 + o], a0); a1 = fmaf(e[d], ub1[d * 64 + o], a1); }
        Bu0[(size_t)n * 64 + o] = a0; Bu1[(size_t)n * 64 + o] = a1;
    }
}

// ------------- W[n,j,o] = sum_d e[n,d] wp[d,j,o], float4 flat -------------
__global__ void k_wpool(const float* NF ne, const float* NF wp, float* NF W,
                        int I2, int O4, int total4) {
    int idx4 = blockIdx.x * 256 + threadIdx.x;
    if (idx4 >= total4) return;
    int o4 = idx4 % O4; int rem = idx4 / O4; int j = rem % I2; int n = rem / I2;
    const float* nrow = ne + n * E_;
    float ax = 0.f, ay = 0.f, az = 0.f, aw = 0.f;
#pragma unroll
    for (int d = 0; d < E_; d++) {
        float e = nrow[d];
        const float4 w = *(const float4*)&wp[(((size_t)d * I2 + j) * O4 + o4) * 4];
        ax = fmaf(e, w.x, ax); ay = fmaf(e, w.y, ay); az = fmaf(e, w.z, az); aw = fmaf(e, w.w, aw);
    }
    float4 r; r.x = ax; r.y = ay; r.z = az; r.w = aw;
    *(float4*)&W[(size_t)idx4 * 4] = r;
}

// ------------- E[tb,i,j] = exp(-L1(pa_i, pa_j)) ; tiled 64x64 -------------
__global__ __launch_bounds__(256) void k_sub_t(const float* NF pa, float* NF Ebuf) {
    int bx = blockIdx.x, tb = blockIdx.y;    // grid (16, 96)
    int it = bx & 3, jt = bx >> 2;
    int t = tb / B_, b = tb % B_;
    const float* p = pa + ((size_t)b * T_ + t) * N_ * H_;
    __shared__ float piT[64][64];
    __shared__ float pjT[64][64];
    int tid = threadIdx.x;
    int i0 = it * 64, j0 = jt * 64;
#pragma unroll
    for (int q = 0; q < 4; q++) {
        int idx = q * 256 + tid; int hq = idx & 15, i = idx >> 4;
        float4 v = *(const float4*)&p[(size_t)(i0 + i) * 64 + hq * 4];
        piT[hq * 4 + 0][i] = v.x; piT[hq * 4 + 1][i] = v.y; piT[hq * 4 + 2][i] = v.z; piT[hq * 4 + 3][i] = v.w;
        float4 w = *(const float4*)&p[(size_t)(j0 + i) * 64 + hq * 4];
        pjT[hq * 4 + 0][i] = w.x; pjT[hq * 4 + 1][i] = w.y; pjT[hq * 4 + 2][i] = w.z; pjT[hq * 4 + 3][i] = w.w;
    }
    __syncthreads();
    int jg = tid & 15, ig = tid >> 4;
    float acc[4][4];
#pragma unroll
    for (int a = 0; a < 4; a++)
#pragma unroll
        for (int c = 0; c < 4; c++) acc[a][c] = 0.f;
    for (int h = 0; h < 64; h++) {
        float4 a4 = *(const float4*)&piT[h][ig * 4];
        float4 b4 = *(const float4*)&pjT[h][jg * 4];
        float av[4] = { a4.x, a4.y, a4.z, a4.w };
        float bv[4] = { b4.x, b4.y, b4.z, b4.w };
#pragma unroll
        for (int a = 0; a < 4; a++)
#pragma unroll
            for (int c = 0; c < 4; c++) acc[a][c] += fabsf(av[a] - bv[c]);
    }
    float* dst = Ebuf + (size_t)tb * N_ * N_;
#pragma unroll
    for (int a = 0; a < 4; a++) {
        float4 o; o.x = __expf(-acc[a][0]); o.y = __expf(-acc[a][1]);
        o.z = __expf(-acc[a][2]); o.w = __expf(-acc[a][3]);
        *(float4*)&dst[(size_t)(i0 + ig * 4 + a) * N_ + j0 + jg * 4] = o;
    }
}

// ------------- inv[tb,j] = 1 / sum_i E[tb,i,j] -------------
__global__ void k_csum(const float* NF Ebuf, float* NF inv) {
    int tb = blockIdx.x, j = threadIdx.x;
    const float* e = Ebuf + (size_t)tb * N_ * N_;
    float S = 0.f;
    for (int i = 0; i < N_; i++) S += e[(size_t)i * N_ + j];
    inv[tb * N_ + j] = 1.f / S;
}

// ------------- A2[tb] = adj @ E[tb]  (64r x 256c tiles, padded SLT) -------------
__global__ __launch_bounds__(256) void k_a2(const float* NF adjm, const float* NF Ebuf, float* NF A2) {
    __shared__ float SLT[32][68];
    __shared__ float UL[32][256];
    int tid = threadIdx.x, cg = tid & 31, rg = tid >> 5;
    int rt = blockIdx.x, tb = blockIdx.y;     // grid (4, 96)
    const float* U = Ebuf + (size_t)tb * N_ * N_;
    float* dst = A2 + (size_t)tb * N_ * N_;
    int r0 = rt * 64;
    float acc[8][8];
#pragma unroll
    for (int r = 0; r < 8; r++)
#pragma unroll
        for (int c = 0; c < 8; c++) acc[r][c] = 0.f;
    for (int ch = 0; ch < 8; ++ch) {
        int m0 = ch * 32;
#pragma unroll
        for (int q = 0; q < 2; ++q) {
            int idx = q * 256 + tid; int mq = idx & 7, r = idx >> 3;
            float4 v = *(const float4*)&adjm[(size_t)(r0 + r) * N_ + m0 + mq * 4];
            SLT[mq * 4 + 0][r] = v.x; SLT[mq * 4 + 1][r] = v.y;
            SLT[mq * 4 + 2][r] = v.z; SLT[mq * 4 + 3][r] = v.w;
        }
#pragma unroll
        for (int q = 0; q < 8; ++q) {
            int i4 = q * 256 + tid; int c4 = i4 & 63, mm = i4 >> 6;
            *(float4*)&UL[mm][c4 * 4] = *(const float4*)&U[(size_t)(m0 + mm) * N_ + c4 * 4];
        }
        __syncthreads();
        for (int mm = 0; mm < 32; ++mm) {
            float sv[8];
            { float4 a = *(const float4*)&SLT[mm][rg * 8];
              float4 b = *(const float4*)&SLT[mm][rg * 8 + 4];
              sv[0] = a.x; sv[1] = a.y; sv[2] = a.z; sv[3] = a.w;
              sv[4] = b.x; sv[5] = b.y; sv[6] = b.z; sv[7] = b.w; }
            float2 uv[4];
#pragma unroll
            for (int uu = 0; uu < 4; uu++) uv[uu] = *(const float2*)&UL[mm][cg * 2 + uu * 64];
#pragma unroll
            for (int r = 0; r < 8; r++) {
#pragma unroll
                for (int uu = 0; uu < 4; uu++) {
                    acc[r][uu * 2]     = fmaf(sv[r], uv[uu].x, acc[r][uu * 2]);
                    acc[r][uu * 2 + 1] = fmaf(sv[r], uv[uu].y, acc[r][uu * 2 + 1]);
                }
            }
        }
        __syncthreads();
    }
#pragma unroll
    for (int r = 0; r < 8; r++) {
        size_t rowoff = (size_t)(r0 + rg * 8 + r) * N_;
#pragma unroll
        for (int uu = 0; uu < 4; uu++) {
            float2 o; o.x = acc[r][uu * 2]; o.y = acc[r][uu * 2 + 1];
            *(float2*)&dst[rowoff + cg * 2 + uu * 64] = o;
        }
    }
}

// ------------- Y0X[((tb*2+k)*N+n)*2+c] = S_k @ (x*inv) -------------
__global__ void k_y0xa(const float* NF s0, const float* NF s1, const float* NF inv,
                       const float* NF x, float* NF y0x) {
    int tb = blockIdx.x, kk = blockIdx.y;
    int t = tb / B_, b = tb % B_;
    const float* S = (kk ? s1 : s0) + (size_t)tb * N_ * N_;
    __shared__ float xw[256][2];
    int n = threadIdx.x;
    { float iv = inv[tb * N_ + n];
      xw[n][0] = x[(((size_t)b * T_ + t) * N_ + n) * 2 + 0] * iv;
      xw[n][1] = x[(((size_t)b * T_ + t) * N_ + n) * 2 + 1] * iv; }
    __syncthreads();
    float a0 = 0.f, a1 = 0.f;
    for (int m = 0; m < N_; m++) {
        float s = S[(size_t)n * N_ + m];
        a0 = fmaf(s, xw[m][0], a0); a1 = fmaf(s, xw[m][1], a1);
    }
    y0x[(((size_t)tb * 2 + kk) * N_ + n) * 2 + 0] = a0;
    y0x[(((size_t)tb * 2 + kk) * N_ + n) * 2 + 1] = a1;
}

// ------------- Y1X = S_k @ (inv*cur0_t), 64x64 tiled (grid 4 x 192) -------------
__global__ __launch_bounds__(256) void k_y1x(const float* NF Ebuf, const float* NF A2,
                                             const float* NF inv, const float* NF cur0,
                                             float* NF y1x) {
    int rt = blockIdx.x, tbk = blockIdx.y;
    int tb = tbk >> 1, kk = tbk & 1;
    int t = tb >> 3, b = tb & 7;
    const float* S = (kk ? A2 : Ebuf) + (size_t)tb * 65536;
    const float* U = cur0 + ((size_t)b * T_ + t) * 16384;
    const float* iv = inv + tb * N_;
    __shared__ float SL[64][65];
    __shared__ float UL[64][72];
    int tid = threadIdx.x;
    int r0 = rt * 64;
    int cg = tid & 15, rg = tid >> 4;
    float acc[4][4];
#pragma unroll
    for (int a = 0; a < 4; a++)
#pragma unroll
        for (int c = 0; c < 4; c++) acc[a][c] = 0.f;
    for (int mc = 0; mc < 4; ++mc) {
        int m0 = mc * 64;
#pragma unroll
        for (int q = 0; q < 4; q++) {
            int idx = q * 256 + tid; int r = idx >> 4, mq = idx & 15;
            float4 v = *(const float4*)&S[(size_t)(r0 + r) * N_ + m0 + mq * 4];
            SL[r][mq * 4 + 0] = v.x; SL[r][mq * 4 + 1] = v.y;
            SL[r][mq * 4 + 2] = v.z; SL[r][mq * 4 + 3] = v.w;
            float4 u = *(const float4*)&U[(size_t)(m0 + r) * 64 + mq * 4];
            float ivv = iv[m0 + r];
            u.x *= ivv; u.y *= ivv; u.z *= ivv; u.w *= ivv;
            *(float4*)&UL[r][mq * 4] = u;
        }
        __syncthreads();
        for (int mm = 0; mm < 64; ++mm) {
            float4 uv = *(const float4*)&UL[mm][cg * 4];
            float sv[4];
#pragma unroll
            for (int a = 0; a < 4; a++) sv[a] = SL[rg * 4 + a][mm];
#pragma unroll
            for (int a = 0; a < 4; a++) {
                acc[a][0] = fmaf(sv[a], uv.x, acc[a][0]);
                acc[a][1] = fmaf(sv[a], uv.y, acc[a][1]);
                acc[a][2] = fmaf(sv[a], uv.z, acc[a][2]);
                acc[a][3] = fmaf(sv[a], uv.w, acc[a][3]);
            }
        }
        __syncthreads();
    }
#pragma unroll
    for (int a = 0; a < 4; a++) {
        float4 o; o.x = acc[a][0]; o.y = acc[a][1]; o.z = acc[a][2]; o.w = acc[a][3];
        *(float4*)&y1x[(((size_t)tb * 2 + kk) * N_ + r0 + rg * 4 + a) * 64 + cg * 4] = o;
    }
}

// ------------- sa init: u1sa = ist_l + pa[:,0] -------------
__global__ void k_init0(const float* NF ist_l, const float* NF pa, float* NF u1) {
    int idx = blockIdx.x * 256 + threadIdx.x;   // 131072
    int b = idx >> 14, rem = idx & 16383;
    u1[idx] = ist_l[idx] + pa[(size_t)b * T_ * 16384 + rem];
}

// ================= phase device functions (bodies = r10 passed kernels) ===========
__device__ __forceinline__ void phaseY_dev(int rt, int kb, int ms, int tid,
    const float* NF S0, const float* NF S1, const float* NF u_in, const float* NF invt,
    float* NF ybuf, float (*SL)[65], float (*UL)[72])
{
    int b = kb >> 1, kk = kb & 1;
    const float* S  = (kk ? S1 : S0) + (size_t)b * 65536;
    const float* ub = u_in + (size_t)b * 16384;
    const float* iv = invt + b * N_;
    int r0 = rt * 64, m0 = ms * 64;
#pragma unroll
    for (int q = 0; q < 4; q++) {
        int idx = q * 256 + tid;
        int r = idx >> 4, mq = idx & 15;
        float4 v = *(const float4*)&S[(size_t)(r0 + r) * N_ + m0 + mq * 4];
        SL[r][mq * 4 + 0] = v.x; SL[r][mq * 4 + 1] = v.y;
        SL[r][mq * 4 + 2] = v.z; SL[r][mq * 4 + 3] = v.w;
        float4 u = *(const float4*)&ub[(size_t)(m0 + r) * 64 + mq * 4];
        float ivv = iv[m0 + r];
        u.x *= ivv; u.y *= ivv; u.z *= ivv; u.w *= ivv;
        *(float4*)&UL[r][mq * 4] = u;
    }
    __syncthreads();
    int cg = tid & 15, rg = tid >> 4;
    float acc[4][4];
#pragma unroll
    for (int a = 0; a < 4; a++)
#pragma unroll
        for (int c = 0; c < 4; c++) acc[a][c] = 0.f;
    for (int mm = 0; mm < 64; ++mm) {
        float4 uv = *(const float4*)&UL[mm][cg * 4];
        float sv[4];
#pragma unroll
        for (int a = 0; a < 4; a++) sv[a] = SL[rg * 4 + a][mm];
#pragma unroll
        for (int a = 0; a < 4; a++) {
            acc[a][0] = fmaf(sv[a], uv.x, acc[a][0]);
            acc[a][1] = fmaf(sv[a], uv.y, acc[a][1]);
            acc[a][2] = fmaf(sv[a], uv.z, acc[a][2]);
            acc[a][3] = fmaf(sv[a], uv.w, acc[a][3]);
        }
    }
#pragma unroll
    for (int a = 0; a < 4; a++) {
        float4 o; o.x = acc[a][0]; o.y = acc[a][1]; o.z = acc[a][2]; o.w = acc[a][3];
        *(float4*)&ybuf[(((size_t)ms * 16 + kb) * N_ + r0 + rg * 4 + a) * 64 + cg * 4] = o;
    }
}

template <int I_, int OTOT, int MODE>
__device__ __forceinline__ void phaseMM_dev(int n, int tid,
    const float* NF ybuf, const float* NF YXt, const float* NF W, const float* NF Bb,
    float* NF u1sa, float* NF u2sa, float* NF rbuf, const float* NF pa,
    float* NF seqout, float* NF hidout, int t, float (*xg)[12])
{
    constexpr int XC = I_ - 64;
    constexpr int J2 = 2 * I_;
    constexpr int BPG = 8 / (256 / OTOT);
    constexpr size_t SS = (size_t)16 * N_ * 64;
    {
        int b = tid >> 5, kk = (tid >> 4) & 1, c = (tid & 15) * 4;
        const float* yp = &ybuf[(((size_t)(b * 2 + kk)) * N_ + n) * 64 + c];
        float4 v = *(const float4*)yp;
        float4 v1 = *(const float4*)(yp + SS);
        float4 v2 = *(const float4*)(yp + 2 * SS);
        float4 v3 = *(const float4*)(yp + 3 * SS);
        v.x += v1.x + v2.x + v3.x; v.y += v1.y + v2.y + v3.y;
        v.z += v1.z + v2.z + v3.z; v.w += v1.w + v2.w + v3.w;
        int j = kk * I_ + XC + c;
        xg[j + 0][b] = v.x; xg[j + 1][b] = v.y; xg[j + 2][b] = v.z; xg[j + 3][b] = v.w;
    }
    if (XC == 64) {
        int b = tid >> 5, kk = (tid >> 4) & 1, c = (tid & 15) * 4;
        float4 v = *(const float4*)&YXt[(((size_t)(b * 2 + kk)) * N_ + n) * 64 + c];
        int j = kk * I_ + c;
        xg[j + 0][b] = v.x; xg[j + 1][b] = v.y; xg[j + 2][b] = v.z; xg[j + 3][b] = v.w;
    } else {
        if (tid < 32) {
            int b = tid >> 2, kk = (tid >> 1) & 1, c = tid & 1;
            xg[kk * I_ + c][b] = YXt[(((size_t)(b * 2 + kk)) * N_ + n) * 2 + c];
        }
    }
    __syncthreads();
    int o = tid % OTOT, bg = tid / OTOT;
    float acc[BPG];
    float bias = Bb[(size_t)n * OTOT + o];
#pragma unroll
    for (int q = 0; q < BPG; ++q) acc[q] = bias;
    const float* Wn = W + (size_t)n * J2 * OTOT + o;
#pragma unroll 4
    for (int j = 0; j < J2; ++j) {
        float w = Wn[(size_t)j * OTOT];
        if (BPG == 4) {
            float4 xv = *(const float4*)&xg[j][bg * 4];
            acc[0] = fmaf(xv.x, w, acc[0]); acc[1] = fmaf(xv.y, w, acc[1]);
            acc[2] = fmaf(xv.z, w, acc[2]); acc[3] = fmaf(xv.w, w, acc[3]);
        } else {
            float2 xv = *(const float2*)&xg[j][bg * 2];
            acc[0] = fmaf(xv.x, w, acc[0]); acc[1] = fmaf(xv.y, w, acc[1]);
        }
    }
#pragma unroll
    for (int q = 0; q < BPG; ++q) {
        int b = bg * BPG + q;
        size_t bn = (size_t)b * N_ + n;
        if (MODE == 0) {
            float v = 1.f / (1.f + __expf(-acc[q]));
            if (o < 64) u2sa[bn * 64 + o] = v * u1sa[bn * 64 + o];   // z*sa
            else        rbuf[bn * 64 + (o - 64)] = v;                // r
        } else {
            float hc = tanhf(acc[q]);
            float r = rbuf[bn * 64 + o];
            float s = u1sa[bn * 64 + o];
            float ns = hc + r * (s - hc);
            seqout[(((size_t)b * T_ + t) * N_ + n) * 64 + o] = ns;
            if (t < T_ - 1) u1sa[bn * 64 + o] = ns + pa[(((size_t)b * T_ + (t + 1)) * N_ + n) * 64 + o];
            else            hidout[bn * 64 + o] = ns;
        }
    }
}

// ================= cooperative persistent per-layer kernel =================
template <int XC>
__global__ __launch_bounds__(256) void k_layer(
    const float* NF Ebuf, const float* NF A2, const float* NF inv, const float* NF YX,
    const float* NF Wg, const float* NF Wu, const float* NF Bg, const float* NF Bu,
    float* NF u1sa, float* NF u2sa, float* NF rbuf, const float* NF pa,
    float* NF seqout, float* NF hidout, float* NF ybuf)
{
    constexpr int I_ = XC + 64;
    __shared__ float smraw[64 * 65 + 64 * 72];   // 35 KB, unioned across phases
    float (*SL)[65] = (float(*)[65])smraw;
    float (*UL)[72] = (float(*)[72])(smraw + 64 * 65);
    float (*xg)[12] = (float(*)[12])smraw;
    cg::grid_group grid = cg::this_grid();
    int bid = blockIdx.x, tid = threadIdx.x;
    int rt = bid & 3, kb = (bid >> 2) & 15, ms = bid >> 6;
    for (int t = 0; t < T_; ++t) {
        const float* Et   = Ebuf + (size_t)t * B_ * 65536;
        const float* A2t  = A2   + (size_t)t * B_ * 65536;
        const float* invt = inv  + (size_t)t * B_ * N_;
        const float* YXt  = YX   + (size_t)t * B_ * 2 * N_ * XC;
        phaseY_dev(rt, kb, ms, tid, Et, A2t, u1sa, invt, ybuf, SL, UL);
        __threadfence(); grid.sync();
        phaseMM_dev<I_, 128, 0>(bid, tid, ybuf, YXt, Wg, Bg, u1sa, u2sa, rbuf, pa, nullptr, nullptr, t, xg);
        __threadfence(); grid.sync();
        phaseY_dev(rt, kb, ms, tid, Et, A2t, u2sa, invt, ybuf, SL, UL);
        __threadfence(); grid.sync();
        phaseMM_dev<I_, 64, 1>(bid, tid, ybuf, YXt, Wu, Bu, u1sa, u2sa, rbuf, pa, seqout, hidout, t, xg);
        __threadfence(); grid.sync();
    }
}

// ================= fallback per-phase kernels (same device funcs) ==========
__global__ __launch_bounds__(256) void k_phY(const float* NF Et, const float* NF A2t,
                                             const float* NF u_in, const float* NF invt,
                                             float* NF ybuf) {
    __shared__ float SL[64][65];
    __shared__ float UL[64][72];
    int bid = blockIdx.x;
    phaseY_dev(bid & 3, (bid >> 2) & 15, bid >> 6, threadIdx.x, Et, A2t, u_in, invt, ybuf, SL, UL);
}
template <int I_, int OTOT, int MODE>
__global__ __launch_bounds__(256) void k_phMM(const float* NF ybuf, const float* NF YXt,
    const float* NF W, const float* NF Bb, float* NF u1sa, float* NF u2sa, float* NF rbuf,
    const float* NF pa, float* NF seqout, float* NF hidout, int t) {
    __shared__ float xg[2 * I_][12];
    phaseMM_dev<I_, OTOT, MODE>(blockIdx.x, threadIdx.x, ybuf, YXt, W, Bb, u1sa, u2sa, rbuf, pa, seqout, hidout, t, xg);
}

extern "C" void kernel_launch(void* const* d_in, const int* in_sizes, int n_in,
                              void* d_out, int out_size, void* d_ws, size_t ws_size,
                              hipStream_t stream) {
    const float* x   = (const float*)d_in[0];
    const float* ist = (const float*)d_in[1];
    const float* ne  = (const float*)d_in[2];
    const float* pa  = (const float*)d_in[3];
    const float* gw0 = (const float*)d_in[4];
    const float* gb0 = (const float*)d_in[5];
    const float* uw0 = (const float*)d_in[6];
    const float* ub0 = (const float*)d_in[7];
    const float* gw1 = (const float*)d_in[8];
    const float* gb1 = (const float*)d_in[9];
    const float* uw1 = (const float*)d_in[10];
    const float* ub1 = (const float*)d_in[11];
    float* out = (float*)d_out;
    char*  base = (char*)d_ws;

    size_t off = 0;
    auto carve = [&](size_t bytes) { char* p = base + off; off += (bytes + 255) & ~(size_t)255; return p; };
    float* adjw = (float*)carve(65536ull * 4);
    float* Ebuf = (float*)carve(6291456ull * 4);
    float* inv  = (float*)carve(24576ull * 4);
    float* Wg   = (float*)carve(8388608ull * 4);
    float* Wu   = (float*)carve(4194304ull * 4);
    float* Bg0  = (float*)carve(32768ull * 4);
    float* Bu0  = (float*)carve(16384ull * 4);
    float* Bg1  = (float*)carve(32768ull * 4);
    float* Bu1  = (float*)carve(16384ull * 4);
    float* u1sa = (float*)carve(131072ull * 4);
    float* u2sa = (float*)carve(131072ull * 4);
    float* rbuf = (float*)carve(131072ull * 4);
    float* y0x  = (float*)carve(98304ull * 4);
    float* y1x  = (float*)carve(3145728ull * 4);
    float* A2   = (float*)carve(6291456ull * 4);
    float* ybuf = (float*)carve((size_t)4 * 16 * 256 * 64 * 4);
    if (off > ws_size) { k_sentinel<<<1, 1, 0, stream>>>(out); return; }

    float* cur_out = out;                                   // (B,T,N,H)
    float* hid_out = out + (size_t)B_ * T_ * N_ * H_;       // (2,B,N,H)
    float* cur0    = cur_out;
    float* hid0    = hid_out;
    float* hid1    = hid_out + 131072;

    // ---- time-invariant precompute ----
    k_adj<<<256, 256, 0, stream>>>(ne, adjw);
    k_sub_t<<<dim3(16, 96), 256, 0, stream>>>(pa, Ebuf);
    k_csum<<<96, 256, 0, stream>>>(Ebuf, inv);
    k_a2<<<dim3(4, 96), 256, 0, stream>>>(adjw, Ebuf, A2);
    k_y0xa<<<dim3(96, 2), 256, 0, stream>>>(Ebuf, A2, inv, x, y0x);
    k_bias4<<<256, 192, 0, stream>>>(ne, gb0, ub0, gb1, ub1, Bg0, Bu0, Bg1, Bu1);

    // ---- layer 0 ----
    {
        int t4g = N_ * 132 * 128 / 4, t4u = N_ * 132 * 64 / 4;
        k_wpool<<<(t4g + 255) / 256, 256, 0, stream>>>(ne, gw0, Wg, 132, 32, t4g);
        k_wpool<<<(t4u + 255) / 256, 256, 0, stream>>>(ne, uw0, Wu, 132, 16, t4u);
        k_init0<<<512, 256, 0, stream>>>(ist, pa, u1sa);
        void* args[15] = { (void*)&Ebuf, (void*)&A2, (void*)&inv, (void*)&y0x,
                           (void*)&Wg, (void*)&Wu, (void*)&Bg0, (void*)&Bu0,
                           (void*)&u1sa, (void*)&u2sa, (void*)&rbuf, (void*)&pa,
                           (void*)&cur0, (void*)&hid0, (void*)&ybuf };
        hipError_t e = hipLaunchCooperativeKernel((const void*)k_layer<2>,
                                                  dim3(256), dim3(256), args, 0, stream);
        if (e != hipSuccess) {
            for (int t = 0; t < T_; t++) {
                const float* Et   = Ebuf + (size_t)t * B_ * 65536;
                const float* A2t  = A2   + (size_t)t * B_ * 65536;
                const float* invt = inv  + (size_t)t * B_ * N_;
                const float* YXt  = y0x  + (size_t)t * B_ * 2 * N_ * 2;
                k_phY<<<256, 256, 0, stream>>>(Et, A2t, u1sa, invt, ybuf);
                k_phMM<66, 128, 0><<<256, 256, 0, stream>>>(ybuf, YXt, Wg, Bg0, u1sa, u2sa, rbuf, pa, nullptr, nullptr, t);
                k_phY<<<256, 256, 0, stream>>>(Et, A2t, u2sa, invt, ybuf);
                k_phMM<66, 64, 1><<<256, 256, 0, stream>>>(ybuf, YXt, Wu, Bu0, u1sa, u2sa, rbuf, pa, cur0, hid0, t);
            }
        }
    }
    // ---- layer 1 ----
    {
        int t4g = N_ * 256 * 128 / 4, t4u = N_ * 256 * 64 / 4;
        k_wpool<<<(t4g + 255) / 256, 256, 0, stream>>>(ne, gw1, Wg, 256, 32, t4g);
        k_wpool<<<(t4u + 255) / 256, 256, 0, stream>>>(ne, uw1, Wu, 256, 16, t4u);
        k_y1x<<<dim3(4, 192), 256, 0, stream>>>(Ebuf, A2, inv, cur0, y1x);
        k_init0<<<512, 256, 0, stream>>>(ist + 131072, pa, u1sa);
        void* args[15] = { (void*)&Ebuf, (void*)&A2, (void*)&inv, (void*)&y1x,
                           (void*)&Wg, (void*)&Wu, (void*)&Bg1, (void*)&Bu1,
                           (void*)&u1sa, (void*)&u2sa, (void*)&rbuf, (void*)&pa,
                           (void*)&cur_out, (void*)&hid1, (void*)&ybuf };
        hipError_t e = hipLaunchCooperativeKernel((const void*)k_layer<64>,
                                                  dim3(256), dim3(256), args, 0, stream);
        if (e != hipSuccess) {
            for (int t = 0; t < T_; t++) {
                const float* Et   = Ebuf + (size_t)t * B_ * 65536;
                const float* A2t  = A2   + (size_t)t * B_ * 65536;
                const float* invt = inv  + (size_t)t * B_ * N_;
                const float* YXt  = y1x  + (size_t)t * B_ * 2 * N_ * 64;
                k_phY<<<256, 256, 0, stream>>>(Et, A2t, u1sa, invt, ybuf);
                k_phMM<128, 128, 0><<<256, 256, 0, stream>>>(ybuf, YXt, Wg, Bg1, u1sa, u2sa, rbuf, pa, nullptr, nullptr, t);
                k_phY<<<256, 256, 0, stream>>>(Et, A2t, u2sa, invt, ybuf);
                k_phMM<128, 64, 1><<<256, 256, 0, stream>>>(ybuf, YXt, Wu, Bu1, u1sa, u2sa, rbuf, pa, cur_out, hid1, t);
            }
        }
    }
    (void)in_sizes; (void)n_in; (void)out_size;
}

// Round 12
// 1268.526 us; speedup vs baseline: 5.1347x; 5.1347x over previous
//
#include <hip/hip_runtime.h>
#include <math.h>

// AVWDCRNN round 12 (all-f32). r11 post-mortem: grid.sync() ~66us on MI355X
// -> cooperative dead end. Back to r10 structure (1343us) with faster kernels:
//  - E/A2 pre-scaled by softmax col-denominator (inv folded in once).
//  - k_y: 32-row tiles, grid 512 (2 blocks/CU).
//  - k_mm: o-sliced (gate grid 256x2).
//  - k_a2 retiled 64x64 (1536 blocks); k_y0x GEMM-tiled; k_y1x from r11; bias4.

#define NF __restrict__
constexpr int N_ = 256, B_ = 8, T_ = 12, H_ = 64, E_ = 16;

__global__ void k_sentinel(float* NF out) { out[0] = 1.0e6f; }

// ---------------- adj = softmax(relu(ne ne^T), axis=1) ----------------
__global__ void k_adj(const float* NF ne, float* NF adj) {
    int n = blockIdx.x, m = threadIdx.x;
    __shared__ float en[E_];
    __shared__ float red[256];
    if (m < E_) en[m] = ne[n * E_ + m];
    __syncthreads();
    float s = 0.f;
#pragma unroll
    for (int d = 0; d < E_; d++) s += en[d] * ne[m * E_ + d];
    s = fmaxf(s, 0.f);
    red[m] = s; __syncthreads();
    for (int st = 128; st > 0; st >>= 1) { if (m < st) red[m] = fmaxf(red[m], red[m + st]); __syncthreads(); }
    float mx = red[0]; __syncthreads();
    float e = __expf(s - mx);
    red[m] = e; __syncthreads();
    for (int st = 128; st > 0; st >>= 1) { if (m < st) red[m] += red[m + st]; __syncthreads(); }
    adj[(size_t)n * N_ + m] = e / red[0];
}

// ------------- all four biases in one launch (grid 256, 192 thr) -------------
__global__ void k_bias4(const float* NF ne, const float* NF gb0, const float* NF ub0,
                        const float* NF gb1, const float* NF ub1,
                        float* NF Bg0, float* NF Bu0, float* NF Bg1, float* NF Bu1) {
    int n = blockIdx.x, tid = threadIdx.x;
    __shared__ float e[E_];
    if (tid < E_) e[tid] = ne[n * E_ + tid];
    __syncthreads();
    if (tid < 128) {
        float a0 = 0.f, a1 = 0.f;
#pragma unroll
        for (int d = 0; d < E_; d++) { a0 = fmaf(e[d], gb0[d * 128 + tid], a0); a1 = fmaf(e[d], gb1[d * 128 + tid], a1); }
        Bg0[(size_t)n * 128 + tid] = a0; Bg1[(size_t)n * 128 + tid] = a1;
    } else {
        int o = tid - 128;
        float a0 = 0.f, a1 = 0.f;
#pragma unroll
        for (int d = 0; d < E_; d++) { a0 = fmaf(e[d], ub0[d * 64 + o], a0); a1 = fmaf(e[d], ub1[d * 64 + o], a1); }
        Bu0[(size_t)n * 64 + o] = a0; Bu1[(size_t)n * 64 + o] = a1;
    }
}

// ------------- W[n,j,o] = sum_d e[n,d] wp[d,j,o], float4 flat -------------
__global__ void k_wpool(const float* NF ne, const float* NF wp, float* NF W,
                        int I2, int O4, int total4) {
    int idx4 = blockIdx.x * 256 + threadIdx.x;
    if (idx4 >= total4) return;
    int o4 = idx4 % O4; int rem = idx4 / O4; int j = rem % I2; int n = rem / I2;
    const float* nrow = ne + n * E_;
    float ax = 0.f, ay = 0.f, az = 0.f, aw = 0.f;
#pragma unroll
    for (int d = 0; d < E_; d++) {
        float e = nrow[d];
        const float4 w = *(const float4*)&wp[(((size_t)d * I2 + j) * O4 + o4) * 4];
        ax = fmaf(e, w.x, ax); ay = fmaf(e, w.y, ay); az = fmaf(e, w.z, az); aw = fmaf(e, w.w, aw);
    }
    float4 r; r.x = ax; r.y = ay; r.z = az; r.w = aw;
    *(float4*)&W[(size_t)idx4 * 4] = r;
}

// ------------- E[tb,i,j] = exp(-L1(pa_i, pa_j)) ; tiled 64x64 -------------
__global__ __launch_bounds__(256) void k_sub_t(const float* NF pa, float* NF Ebuf) {
    int bx = blockIdx.x, tb = blockIdx.y;    // grid (16, 96)
    int it = bx & 3, jt = bx >> 2;
    int t = tb / B_, b = tb % B_;
    const float* p = pa + ((size_t)b * T_ + t) * N_ * H_;
    __shared__ float piT[64][64];
    __shared__ float pjT[64][64];
    int tid = threadIdx.x;
    int i0 = it * 64, j0 = jt * 64;
#pragma unroll
    for (int q = 0; q < 4; q++) {
        int idx = q * 256 + tid; int hq = idx & 15, i = idx >> 4;
        float4 v = *(const float4*)&p[(size_t)(i0 + i) * 64 + hq * 4];
        piT[hq * 4 + 0][i] = v.x; piT[hq * 4 + 1][i] = v.y; piT[hq * 4 + 2][i] = v.z; piT[hq * 4 + 3][i] = v.w;
        float4 w = *(const float4*)&p[(size_t)(j0 + i) * 64 + hq * 4];
        pjT[hq * 4 + 0][i] = w.x; pjT[hq * 4 + 1][i] = w.y; pjT[hq * 4 + 2][i] = w.z; pjT[hq * 4 + 3][i] = w.w;
    }
    __syncthreads();
    int jg = tid & 15, ig = tid >> 4;
    float acc[4][4];
#pragma unroll
    for (int a = 0; a < 4; a++)
#pragma unroll
        for (int c = 0; c < 4; c++) acc[a][c] = 0.f;
    for (int h = 0; h < 64; h++) {
        float4 a4 = *(const float4*)&piT[h][ig * 4];
        float4 b4 = *(const float4*)&pjT[h][jg * 4];
        float av[4] = { a4.x, a4.y, a4.z, a4.w };
        float bv[4] = { b4.x, b4.y, b4.z, b4.w };
#pragma unroll
        for (int a = 0; a < 4; a++)
#pragma unroll
            for (int c = 0; c < 4; c++) acc[a][c] += fabsf(av[a] - bv[c]);
    }
    float* dst = Ebuf + (size_t)tb * N_ * N_;
#pragma unroll
    for (int a = 0; a < 4; a++) {
        float4 o; o.x = __expf(-acc[a][0]); o.y = __expf(-acc[a][1]);
        o.z = __expf(-acc[a][2]); o.w = __expf(-acc[a][3]);
        *(float4*)&dst[(size_t)(i0 + ig * 4 + a) * N_ + j0 + jg * 4] = o;
    }
}

// ------------- inv[tb,j] = 1 / sum_i E[tb,i,j] -------------
__global__ void k_csum(const float* NF Ebuf, float* NF inv) {
    int tb = blockIdx.x, j = threadIdx.x;
    const float* e = Ebuf + (size_t)tb * N_ * N_;
    float S = 0.f;
    for (int i = 0; i < N_; i++) S += e[(size_t)i * N_ + j];
    inv[tb * N_ + j] = 1.f / S;
}

// ------------- E[tb,i,j] *= inv[tb,j]  (column scale, float4) -------------
__global__ void k_scaleE(float* NF Ebuf, const float* NF inv) {
    size_t idx4 = (size_t)blockIdx.x * 256 + threadIdx.x;   // 1572864 total, grid 6144
    int j4 = (int)(idx4 & 63); size_t row = idx4 >> 6; int tb = (int)(row >> 8);
    float4 v = ((float4*)Ebuf)[idx4];
    float4 iv = *(const float4*)&inv[tb * N_ + j4 * 4];
    v.x *= iv.x; v.y *= iv.y; v.z *= iv.z; v.w *= iv.w;
    ((float4*)Ebuf)[idx4] = v;
}

// ------------- A2[tb] = adj @ E'[tb]  (64x64 tiles, grid (16, 96)) -------------
__global__ __launch_bounds__(256) void k_a2(const float* NF adjm, const float* NF Ebuf, float* NF A2) {
    int rt = blockIdx.x & 3, ct = blockIdx.x >> 2;
    int tb = blockIdx.y;
    const float* U = Ebuf + (size_t)tb * N_ * N_;
    int r0 = rt * 64, c0 = ct * 64;
    __shared__ float SL[64][65];
    __shared__ float UL[64][72];
    int tid = threadIdx.x, cg = tid & 15, rg = tid >> 4;
    float acc[4][4];
#pragma unroll
    for (int a = 0; a < 4; a++)
#pragma unroll
        for (int c = 0; c < 4; c++) acc[a][c] = 0.f;
    for (int mc = 0; mc < 4; ++mc) {
        int m0 = mc * 64;
#pragma unroll
        for (int q = 0; q < 4; q++) {
            int idx = q * 256 + tid; int r = idx >> 4, mq = idx & 15;
            float4 v = *(const float4*)&adjm[(size_t)(r0 + r) * N_ + m0 + mq * 4];
            SL[r][mq * 4 + 0] = v.x; SL[r][mq * 4 + 1] = v.y;
            SL[r][mq * 4 + 2] = v.z; SL[r][mq * 4 + 3] = v.w;
            float4 u = *(const float4*)&U[(size_t)(m0 + r) * N_ + c0 + mq * 4];
            *(float4*)&UL[r][mq * 4] = u;
        }
        __syncthreads();
        for (int mm = 0; mm < 64; ++mm) {
            float4 uv = *(const float4*)&UL[mm][cg * 4];
            float sv[4];
#pragma unroll
            for (int a = 0; a < 4; a++) sv[a] = SL[rg * 4 + a][mm];
#pragma unroll
            for (int a = 0; a < 4; a++) {
                acc[a][0] = fmaf(sv[a], uv.x, acc[a][0]);
                acc[a][1] = fmaf(sv[a], uv.y, acc[a][1]);
                acc[a][2] = fmaf(sv[a], uv.z, acc[a][2]);
                acc[a][3] = fmaf(sv[a], uv.w, acc[a][3]);
            }
        }
        __syncthreads();
    }
    float* dst = A2 + (size_t)tb * N_ * N_;
#pragma unroll
    for (int a = 0; a < 4; a++) {
        float4 o; o.x = acc[a][0]; o.y = acc[a][1]; o.z = acc[a][2]; o.w = acc[a][3];
        *(float4*)&dst[(size_t)(r0 + rg * 4 + a) * N_ + c0 + cg * 4] = o;
    }
}

// ------------- Y0X = S'_k @ x  (64-row tiles, 4-way m-split + shfl reduce) -------------
__global__ __launch_bounds__(256) void k_y0x(const float* NF Ebuf, const float* NF A2,
                                             const float* NF x, float* NF y0x) {
    int rt = blockIdx.x, tbk = blockIdx.y;   // grid (4, 192)
    int tb = tbk >> 1, kk = tbk & 1;
    int t = tb / B_, b = tb % B_;
    const float* S = (kk ? A2 : Ebuf) + (size_t)tb * N_ * N_;
    const float* xb = x + ((size_t)b * T_ + t) * N_ * 2;
    __shared__ float SL[64][65];
    __shared__ float xw[64][2];
    int tid = threadIdx.x, rg = tid >> 2, mg = tid & 3;
    int r0 = rt * 64;
    float a0 = 0.f, a1 = 0.f;
    for (int mc = 0; mc < 4; ++mc) {
        int m0 = mc * 64;
#pragma unroll
        for (int q = 0; q < 4; q++) {
            int idx = q * 256 + tid; int r = idx >> 4, mq = idx & 15;
            float4 v = *(const float4*)&S[(size_t)(r0 + r) * N_ + m0 + mq * 4];
            SL[r][mq * 4 + 0] = v.x; SL[r][mq * 4 + 1] = v.y;
            SL[r][mq * 4 + 2] = v.z; SL[r][mq * 4 + 3] = v.w;
        }
        if (tid < 128) xw[tid >> 1][tid & 1] = xb[(size_t)(m0 + (tid >> 1)) * 2 + (tid & 1)];
        __syncthreads();
        for (int mm = mg * 16; mm < mg * 16 + 16; ++mm) {
            float s = SL[rg][mm];
            a0 = fmaf(s, xw[mm][0], a0); a1 = fmaf(s, xw[mm][1], a1);
        }
        __syncthreads();
    }
    a0 += __shfl_xor(a0, 1); a0 += __shfl_xor(a0, 2);
    a1 += __shfl_xor(a1, 1); a1 += __shfl_xor(a1, 2);
    if (mg == 0) {
        y0x[(((size_t)tb * 2 + kk) * N_ + r0 + rg) * 2 + 0] = a0;
        y0x[(((size_t)tb * 2 + kk) * N_ + r0 + rg) * 2 + 1] = a1;
    }
}

// ------------- Y1X = S'_k @ cur0_t  (64x64 tiles, grid (4, 192)) -------------
__global__ __launch_bounds__(256) void k_y1x(const float* NF Ebuf, const float* NF A2,
                                             const float* NF cur0, float* NF y1x) {
    int rt = blockIdx.x, tbk = blockIdx.y;
    int tb = tbk >> 1, kk = tbk & 1;
    int t = tb >> 3, b = tb & 7;
    const float* S = (kk ? A2 : Ebuf) + (size_t)tb * 65536;
    const float* U = cur0 + ((size_t)b * T_ + t) * 16384;
    __shared__ float SL[64][65];
    __shared__ float UL[64][72];
    int tid = threadIdx.x;
    int r0 = rt * 64;
    int cg = tid & 15, rg = tid >> 4;
    float acc[4][4];
#pragma unroll
    for (int a = 0; a < 4; a++)
#pragma unroll
        for (int c = 0; c < 4; c++) acc[a][c] = 0.f;
    for (int mc = 0; mc < 4; ++mc) {
        int m0 = mc * 64;
#pragma unroll
        for (int q = 0; q < 4; q++) {
            int idx = q * 256 + tid; int r = idx >> 4, mq = idx & 15;
            float4 v = *(const float4*)&S[(size_t)(r0 + r) * N_ + m0 + mq * 4];
            SL[r][mq * 4 + 0] = v.x; SL[r][mq * 4 + 1] = v.y;
            SL[r][mq * 4 + 2] = v.z; SL[r][mq * 4 + 3] = v.w;
            float4 u = *(const float4*)&U[(size_t)(m0 + r) * 64 + mq * 4];
            *(float4*)&UL[r][mq * 4] = u;
        }
        __syncthreads();
        for (int mm = 0; mm < 64; ++mm) {
            float4 uv = *(const float4*)&UL[mm][cg * 4];
            float sv[4];
#pragma unroll
            for (int a = 0; a < 4; a++) sv[a] = SL[rg * 4 + a][mm];
#pragma unroll
            for (int a = 0; a < 4; a++) {
                acc[a][0] = fmaf(sv[a], uv.x, acc[a][0]);
                acc[a][1] = fmaf(sv[a], uv.y, acc[a][1]);
                acc[a][2] = fmaf(sv[a], uv.z, acc[a][2]);
                acc[a][3] = fmaf(sv[a], uv.w, acc[a][3]);
            }
        }
        __syncthreads();
    }
#pragma unroll
    for (int a = 0; a < 4; a++) {
        float4 o; o.x = acc[a][0]; o.y = acc[a][1]; o.z = acc[a][2]; o.w = acc[a][3];
        *(float4*)&y1x[(((size_t)tb * 2 + kk) * N_ + r0 + rg * 4 + a) * 64 + cg * 4] = o;
    }
}

// ------------- sa init: u1sa = ist_l + pa[:,0] -------------
__global__ void k_init0(const float* NF ist_l, const float* NF pa, float* NF u1) {
    int idx = blockIdx.x * 256 + threadIdx.x;   // 131072
    int b = idx >> 14, rem = idx & 16383;
    u1[idx] = ist_l[idx] + pa[(size_t)b * T_ * 16384 + rem];
}

// ------------- per-step y GEMM: 32-row tiles, grid (8 rt, 16 kb, 4 ms) -------------
__global__ __launch_bounds__(256) void k_y(const float* NF S0, const float* NF S1,
                                           const float* NF u_in, float* NF ybuf) {
    int rt = blockIdx.x, kb = blockIdx.y, ms = blockIdx.z;
    int b = kb >> 1, kk = kb & 1;
    const float* S  = (kk ? S1 : S0) + (size_t)b * 65536;
    const float* ub = u_in + (size_t)b * 16384;
    int r0 = rt * 32, m0 = ms * 64;
    __shared__ float SL[32][65];
    __shared__ float UL[64][72];
    int tid = threadIdx.x;
#pragma unroll
    for (int q = 0; q < 2; q++) {
        int idx = q * 256 + tid; int r = idx >> 4, mq = idx & 15;
        float4 v = *(const float4*)&S[(size_t)(r0 + r) * N_ + m0 + mq * 4];
        SL[r][mq * 4 + 0] = v.x; SL[r][mq * 4 + 1] = v.y;
        SL[r][mq * 4 + 2] = v.z; SL[r][mq * 4 + 3] = v.w;
    }
#pragma unroll
    for (int q = 0; q < 4; q++) {
        int idx = q * 256 + tid; int mm = idx >> 4, cq = idx & 15;
        *(float4*)&UL[mm][cq * 4] = *(const float4*)&ub[(size_t)(m0 + mm) * 64 + cq * 4];
    }
    __syncthreads();
    int cg = tid & 15, rg = tid >> 4;
    float acc[2][4];
#pragma unroll
    for (int a = 0; a < 2; a++)
#pragma unroll
        for (int c = 0; c < 4; c++) acc[a][c] = 0.f;
    for (int mm = 0; mm < 64; ++mm) {
        float4 uv = *(const float4*)&UL[mm][cg * 4];
        float s0 = SL[rg * 2 + 0][mm], s1 = SL[rg * 2 + 1][mm];
        acc[0][0] = fmaf(s0, uv.x, acc[0][0]); acc[0][1] = fmaf(s0, uv.y, acc[0][1]);
        acc[0][2] = fmaf(s0, uv.z, acc[0][2]); acc[0][3] = fmaf(s0, uv.w, acc[0][3]);
        acc[1][0] = fmaf(s1, uv.x, acc[1][0]); acc[1][1] = fmaf(s1, uv.y, acc[1][1]);
        acc[1][2] = fmaf(s1, uv.z, acc[1][2]); acc[1][3] = fmaf(s1, uv.w, acc[1][3]);
    }
#pragma unroll
    for (int a = 0; a < 2; a++) {
        float4 o; o.x = acc[a][0]; o.y = acc[a][1]; o.z = acc[a][2]; o.w = acc[a][3];
        *(float4*)&ybuf[(((size_t)ms * 16 + kb) * N_ + r0 + rg * 2 + a) * 64 + cg * 4] = o;
    }
}

// ------------- per-node mm + fused GRU epilogue (o-sliced, grid (256, OTOT/64)) ------
template <int I_, int OTOT, int MODE>
__global__ __launch_bounds__(256) void k_mm(
    const float* NF ybuf, const float* NF YXt, const float* NF W, const float* NF Bb,
    float* NF u1sa, float* NF u2sa, float* NF rbuf, const float* NF pa,
    float* NF seqout, float* NF hidout, int t)
{
    constexpr int XC = I_ - 64;
    constexpr int J2 = 2 * I_;
    constexpr size_t SS = (size_t)16 * N_ * 64;   // ybuf slot stride
    int n = blockIdx.x, os = blockIdx.y, tid = threadIdx.x;
    __shared__ float xg[J2][12];
    // sa-part: sum 4 m-split slots
    {
        int b = tid >> 5, kk = (tid >> 4) & 1, c = (tid & 15) * 4;
        const float* yp = &ybuf[(((size_t)(b * 2 + kk)) * N_ + n) * 64 + c];
        float4 v = *(const float4*)yp;
        float4 v1 = *(const float4*)(yp + SS);
        float4 v2 = *(const float4*)(yp + 2 * SS);
        float4 v3 = *(const float4*)(yp + 3 * SS);
        v.x += v1.x + v2.x + v3.x; v.y += v1.y + v2.y + v3.y;
        v.z += v1.z + v2.z + v3.z; v.w += v1.w + v2.w + v3.w;
        int j = kk * I_ + XC + c;
        xg[j + 0][b] = v.x; xg[j + 1][b] = v.y; xg[j + 2][b] = v.z; xg[j + 3][b] = v.w;
    }
    if (XC == 64) {
        int b = tid >> 5, kk = (tid >> 4) & 1, c = (tid & 15) * 4;
        float4 v = *(const float4*)&YXt[(((size_t)(b * 2 + kk)) * N_ + n) * 64 + c];
        int j = kk * I_ + c;
        xg[j + 0][b] = v.x; xg[j + 1][b] = v.y; xg[j + 2][b] = v.z; xg[j + 3][b] = v.w;
    } else {
        if (tid < 32) {
            int b = tid >> 2, kk = (tid >> 1) & 1, c = tid & 1;
            xg[kk * I_ + c][b] = YXt[(((size_t)(b * 2 + kk)) * N_ + n) * 2 + c];
        }
    }
    __syncthreads();
    int o = os * 64 + (tid & 63);
    int bg = tid >> 6;                       // 0..3, BPG=2
    float acc[2];
    float bias = Bb[(size_t)n * OTOT + o];
    acc[0] = bias; acc[1] = bias;
    const float* Wn = W + (size_t)n * J2 * OTOT + o;
#pragma unroll 4
    for (int j = 0; j < J2; ++j) {
        float w = Wn[(size_t)j * OTOT];
        float2 xv = *(const float2*)&xg[j][bg * 2];
        acc[0] = fmaf(xv.x, w, acc[0]); acc[1] = fmaf(xv.y, w, acc[1]);
    }
#pragma unroll
    for (int q = 0; q < 2; ++q) {
        int b = bg * 2 + q;
        size_t bn = (size_t)b * N_ + n;
        if (MODE == 0) {
            float v = 1.f / (1.f + __expf(-acc[q]));
            if (o < 64) u2sa[bn * 64 + o] = v * u1sa[bn * 64 + o];   // z*sa
            else        rbuf[bn * 64 + (o - 64)] = v;                // r
        } else {
            float hc = tanhf(acc[q]);
            float r = rbuf[bn * 64 + o];
            float s = u1sa[bn * 64 + o];
            float ns = hc + r * (s - hc);
            seqout[(((size_t)b * T_ + t) * N_ + n) * 64 + o] = ns;
            if (t < T_ - 1) u1sa[bn * 64 + o] = ns + pa[(((size_t)b * T_ + (t + 1)) * N_ + n) * 64 + o];
            else            hidout[bn * 64 + o] = ns;
        }
    }
}

extern "C" void kernel_launch(void* const* d_in, const int* in_sizes, int n_in,
                              void* d_out, int out_size, void* d_ws, size_t ws_size,
                              hipStream_t stream) {
    const float* x   = (const float*)d_in[0];
    const float* ist = (const float*)d_in[1];
    const float* ne  = (const float*)d_in[2];
    const float* pa  = (const float*)d_in[3];
    const float* gw0 = (const float*)d_in[4];
    const float* gb0 = (const float*)d_in[5];
    const float* uw0 = (const float*)d_in[6];
    const float* ub0 = (const float*)d_in[7];
    const float* gw1 = (const float*)d_in[8];
    const float* gb1 = (const float*)d_in[9];
    const float* uw1 = (const float*)d_in[10];
    const float* ub1 = (const float*)d_in[11];
    float* out = (float*)d_out;
    char*  base = (char*)d_ws;

    size_t off = 0;
    auto carve = [&](size_t bytes) { char* p = base + off; off += (bytes + 255) & ~(size_t)255; return p; };
    float* adjw = (float*)carve(65536ull * 4);
    float* Ebuf = (float*)carve(6291456ull * 4);
    float* inv  = (float*)carve(24576ull * 4);
    float* Wg   = (float*)carve(8388608ull * 4);
    float* Wu   = (float*)carve(4194304ull * 4);
    float* Bg0  = (float*)carve(32768ull * 4);
    float* Bu0  = (float*)carve(16384ull * 4);
    float* Bg1  = (float*)carve(32768ull * 4);
    float* Bu1  = (float*)carve(16384ull * 4);
    float* u1sa = (float*)carve(131072ull * 4);
    float* u2sa = (float*)carve(131072ull * 4);
    float* rbuf = (float*)carve(131072ull * 4);
    float* y0x  = (float*)carve(98304ull * 4);
    float* y1x  = (float*)carve(3145728ull * 4);
    float* A2   = (float*)carve(6291456ull * 4);
    float* ybuf = (float*)carve((size_t)4 * 16 * 256 * 64 * 4);
    if (off > ws_size) { k_sentinel<<<1, 1, 0, stream>>>(out); return; }

    float* cur_out = out;                                   // (B,T,N,H)
    float* hid_out = out + (size_t)B_ * T_ * N_ * H_;       // (2,B,N,H)
    float* cur0    = cur_out;

    // ---- time-invariant precompute ----
    k_adj<<<256, 256, 0, stream>>>(ne, adjw);
    k_sub_t<<<dim3(16, 96), 256, 0, stream>>>(pa, Ebuf);
    k_csum<<<96, 256, 0, stream>>>(Ebuf, inv);
    k_scaleE<<<6144, 256, 0, stream>>>(Ebuf, inv);
    k_a2<<<dim3(16, 96), 256, 0, stream>>>(adjw, Ebuf, A2);
    k_y0x<<<dim3(4, 192), 256, 0, stream>>>(Ebuf, A2, x, y0x);
    k_bias4<<<256, 192, 0, stream>>>(ne, gb0, ub0, gb1, ub1, Bg0, Bu0, Bg1, Bu1);

    // ---- layer 0 ----
    {
        int t4g = N_ * 132 * 128 / 4, t4u = N_ * 132 * 64 / 4;
        k_wpool<<<(t4g + 255) / 256, 256, 0, stream>>>(ne, gw0, Wg, 132, 32, t4g);
        k_wpool<<<(t4u + 255) / 256, 256, 0, stream>>>(ne, uw0, Wu, 132, 16, t4u);
        k_init0<<<512, 256, 0, stream>>>(ist, pa, u1sa);
        for (int t = 0; t < T_; t++) {
            const float* Et   = Ebuf + (size_t)t * B_ * 65536;
            const float* A2t  = A2   + (size_t)t * B_ * 65536;
            const float* YXt  = y0x  + (size_t)t * B_ * 2 * N_ * 2;
            k_y<<<dim3(8, 16, 4), 256, 0, stream>>>(Et, A2t, u1sa, ybuf);
            k_mm<66, 128, 0><<<dim3(256, 2), 256, 0, stream>>>(ybuf, YXt, Wg, Bg0, u1sa, u2sa, rbuf, pa, nullptr, nullptr, t);
            k_y<<<dim3(8, 16, 4), 256, 0, stream>>>(Et, A2t, u2sa, ybuf);
            k_mm<66, 64, 1><<<dim3(256, 1), 256, 0, stream>>>(ybuf, YXt, Wu, Bu0, u1sa, u2sa, rbuf, pa, cur0, hid_out, t);
        }
    }
    // ---- layer 1 ----
    {
        int t4g = N_ * 256 * 128 / 4, t4u = N_ * 256 * 64 / 4;
        k_wpool<<<(t4g + 255) / 256, 256, 0, stream>>>(ne, gw1, Wg, 256, 32, t4g);
        k_wpool<<<(t4u + 255) / 256, 256, 0, stream>>>(ne, uw1, Wu, 256, 16, t4u);
        k_y1x<<<dim3(4, 192), 256, 0, stream>>>(Ebuf, A2, cur0, y1x);
        k_init0<<<512, 256, 0, stream>>>(ist + 131072, pa, u1sa);
        for (int t = 0; t < T_; t++) {
            const float* Et   = Ebuf + (size_t)t * B_ * 65536;
            const float* A2t  = A2   + (size_t)t * B_ * 65536;
            const float* YXt  = y1x  + (size_t)t * B_ * 2 * N_ * 64;
            k_y<<<dim3(8, 16, 4), 256, 0, stream>>>(Et, A2t, u1sa, ybuf);
            k_mm<128, 128, 0><<<dim3(256, 2), 256, 0, stream>>>(ybuf, YXt, Wg, Bg1, u1sa, u2sa, rbuf, pa, nullptr, nullptr, t);
            k_y<<<dim3(8, 16, 4), 256, 0, stream>>>(Et, A2t, u2sa, ybuf);
            k_mm<128, 64, 1><<<dim3(256, 1), 256, 0, stream>>>(ybuf, YXt, Wu, Bu1, u1sa, u2sa, rbuf, pa, cur_out, hid_out + 131072, t);
        }
    }
    (void)in_sizes; (void)n_in; (void)out_size;
}